// Round 15
// baseline (73.619 us; speedup 1.0000x reference)
//
#include <hip/hip_runtime.h>

// DIN attention pooling — round 15: operand-swapped MFMA, zero LDS transpose.
//   Wb[e][h] = (W1b-W1c)[e][h] + q_e*W1d[e][h];  qh[h] = b1[h] + q @ (W1a+W1c)
//   H = sig(K@Wb + qh); G = sig(H@W2 + b2); s = G@W3 + b3 (masked); out = s^T K
// Fragment-layout identity (16x16x32): A-frag lane l = A[l15][l4*8+j]; B-frag
// lane l = B[l4*8+j][l15] — same registers serve as A of M or B of M^T. So
// L1 computed SWAPPED: mfma(A=Wb^T frags, B=keys frags) = H^T, whose C-layout
// (lane: col t=l15, row h=16n+l4*4+i) IS the A-frag layout of the legacy
// 16x16x16f16 MFMA (k = l4*4+j). sigmoid+cvt_pkrtz packs accumulators directly
// into L2 A-frags: H never touches LDS (R14 proved the slab chain can't be
// pipelined at source level — lgkmcnt in-order drain).
// REGISTER LAW (R6/R8/R11 vs R7/R9/R12): keep the 170-reg class (bound ,3).

constexpr int Bn = 2048, Tn = 200, En = 64;

typedef _Float16 f16;
typedef _Float16 f16x2 __attribute__((ext_vector_type(2)));
typedef _Float16 f16x4 __attribute__((ext_vector_type(4)));
typedef _Float16 f16x8 __attribute__((ext_vector_type(8)));
typedef float f32x4 __attribute__((ext_vector_type(4)));

__device__ __align__(16) f16 g_wkf[80 * 64];    // [h][e]  W1b - W1c
__device__ __align__(16) f16 g_wqf[80 * 64];    // [h][e]  W1d
__device__ __align__(16) f16 g_wsumT[80 * 64];  // [h][e]  W1a + W1c
__device__ __align__(16) f16 g_w2f[3 * 5 * 64 * 4];  // L2 B-frags: slot=(colt*5+n)*64+lane

__device__ __forceinline__ float fsig(float x) {
  return __fdividef(1.0f, 1.0f + __expf(-x));
}

template <int CTRL>
__device__ __forceinline__ float dpp_add(float x) {
  int y = __builtin_amdgcn_update_dpp(0, __builtin_bit_cast(int, x),
                                      CTRL, 0xf, 0xf, true);
  return x + __builtin_bit_cast(float, y);
}
__device__ __forceinline__ float row16_sum(float x) {
  x = dpp_add<0x121>(x);
  x = dpp_add<0x122>(x);
  x = dpp_add<0x124>(x);
  x = dpp_add<0x128>(x);
  return x;
}

__device__ __forceinline__ f16x8 pack8(float4 a, float4 b) {
  union { f16x2 p[4]; f16x8 v; } u;
  u.p[0] = __builtin_bit_cast(f16x2, __builtin_amdgcn_cvt_pkrtz(a.x, a.y));
  u.p[1] = __builtin_bit_cast(f16x2, __builtin_amdgcn_cvt_pkrtz(a.z, a.w));
  u.p[2] = __builtin_bit_cast(f16x2, __builtin_amdgcn_cvt_pkrtz(b.x, b.y));
  u.p[3] = __builtin_bit_cast(f16x2, __builtin_amdgcn_cvt_pkrtz(b.z, b.w));
  return u.v;
}
__device__ __forceinline__ f16x4 pack4(float a, float b, float c, float d) {
  union { f16x2 p[2]; f16x4 v; } u;
  u.p[0] = __builtin_bit_cast(f16x2, __builtin_amdgcn_cvt_pkrtz(a, b));
  u.p[1] = __builtin_bit_cast(f16x2, __builtin_amdgcn_cvt_pkrtz(c, d));
  return u.v;
}

__global__ __launch_bounds__(256) void din_prep(const float* __restrict__ W1,
                                                const float* __restrict__ W2) {
  int idx = blockIdx.x * 256 + threadIdx.x;   // grid 20 -> 5120
  if (idx < 5120) {
    int h = idx >> 6, e = idx & 63;
    float wa = W1[e * 80 + h], wb = W1[(64 + e) * 80 + h];
    float wc = W1[(128 + e) * 80 + h], wd = W1[(192 + e) * 80 + h];
    g_wkf[idx] = (f16)(wb - wc);
    g_wqf[idx] = (f16)wd;
    g_wsumT[idx] = (f16)(wa + wc);
  }
  if (idx < 960) {   // L2 B-frags for mfma_16x16x16f16: B[k=16n+l4*4+j][col=colt*16+l15]
    int colt = idx / 320, rem = idx % 320;
    int n = rem >> 6, lane = rem & 63;
    int l4 = lane >> 4, l15 = lane & 15;
    int j2 = colt * 16 + l15;
    f16x4 v;
    #pragma unroll
    for (int j = 0; j < 4; ++j) {
      int h = 16 * n + l4 * 4 + j;
      v[j] = (j2 < 40) ? (f16)W2[h * 40 + j2] : (f16)0.0f;
    }
    *(f16x4*)&g_w2f[idx * 4] = v;
  }
}

__global__ __launch_bounds__(64, 3) void din_main(
    const float* __restrict__ query,
    const float* __restrict__ keys,
    const int*   __restrict__ keys_length,
    const float* __restrict__ b1,
    const float* __restrict__ b2,
    const float* __restrict__ W3,
    const float* __restrict__ b3,
    float* __restrict__ out)
{
  __shared__ float sSw[16];

  const int lane = threadIdx.x;
  const int l15 = lane & 15;
  const int l4  = lane >> 4;

  const int b    = blockIdx.x >> 1;
  const int half = blockIdx.x & 1;
  const int mts  = half ? 7 : 0;
  const int mte  = half ? 13 : 7;

  const float* qp = query + (size_t)b * En;
  const float* kb = keys + (size_t)b * Tn * En;
  const int len = keys_length[b];
  const float b3v = b3[0];

  // ---- q fragments (f16) ----
  f16x8 qf0, qf1;
  {
    float4 qa = *(const float4*)(qp + l4 * 8);
    float4 qb = *(const float4*)(qp + l4 * 8 + 4);
    float4 qc = *(const float4*)(qp + 32 + l4 * 8);
    float4 qd = *(const float4*)(qp + 32 + l4 * 8 + 4);
    qf0 = pack8(qa, qb);
    qf1 = pack8(qc, qd);
  }

  // ---- qh[c] = b1[c] + q @ wsum[:,c] (c = n*16+l15), then redistribute to
  //      qh2[n][i] = qh[16n + l4*4 + i] (the swapped-L1 accumulator layout) ----
  float qh2[5][4];
  #pragma unroll
  for (int n = 0; n < 5; ++n) {
    int c = n * 16 + l15;
    f16x8 ws0 = *(const f16x8*)&g_wsumT[c * 64 + l4 * 8];
    f16x8 ws1 = *(const f16x8*)&g_wsumT[c * 64 + 32 + l4 * 8];
    float p = 0.f;
    #pragma unroll
    for (int j = 0; j < 8; ++j)
      p += (float)qf0[j] * (float)ws0[j] + (float)qf1[j] * (float)ws1[j];
    p += __shfl_xor(p, 16, 64);
    p += __shfl_xor(p, 32, 64);
    float qhn = p + b1[c];           // qh[n*16+l15], uniform over l4
    #pragma unroll
    for (int i = 0; i < 4; ++i)
      qh2[n][i] = __shfl(qhn, l4 * 4 + i, 64);
  }

  // ---- Wb^T fragments: Wb = wk + q*wqk (elementwise f16); serve as MFMA A ----
  f16x8 bf0[5], bf1[5];
  #pragma unroll
  for (int n = 0; n < 5; ++n) {
    int c = n * 16 + l15;
    bf0[n] = *(const f16x8*)&g_wkf[c * 64 + l4 * 8]
           + qf0 * *(const f16x8*)&g_wqf[c * 64 + l4 * 8];
    bf1[n] = *(const f16x8*)&g_wkf[c * 64 + 32 + l4 * 8]
           + qf1 * *(const f16x8*)&g_wqf[c * 64 + 32 + l4 * 8];
  }

  // ---- per-col constants for L2/L3 (L2 output col = colt*16 + l15) ----
  float b2v[3], w3v[3];
  #pragma unroll
  for (int n = 0; n < 3; ++n) {
    int c = n * 16 + l15;
    b2v[n] = (c < 40) ? b2[c] : 0.0f;
    w3v[n] = (c < 40) ? W3[c] : 0.0f;
  }

  float poolA[8] = {0,0,0,0,0,0,0,0};
  float poolB[8] = {0,0,0,0,0,0,0,0};

  // ---- prefetch first tile's keys rows ----
  float4 p0, p1, p2, p3;
  {
    int r = mts * 16 + l15; const float* kr = kb + (r < Tn ? r : Tn - 1) * 64;
    p0 = *(const float4*)(kr + l4 * 8);
    p1 = *(const float4*)(kr + l4 * 8 + 4);
    p2 = *(const float4*)(kr + 32 + l4 * 8);
    p3 = *(const float4*)(kr + 32 + l4 * 8 + 4);
  }

  for (int mt = mts; mt < mte; ++mt) {
    f16x8 ka = pack8(p0, p1);
    f16x8 kc = pack8(p2, p3);
    if (mt + 1 < mte) {
      int r = (mt + 1) * 16 + l15; const float* kr = kb + (r < Tn ? r : Tn - 1) * 64;
      p0 = *(const float4*)(kr + l4 * 8);
      p1 = *(const float4*)(kr + l4 * 8 + 4);
      p2 = *(const float4*)(kr + 32 + l4 * 8);
      p3 = *(const float4*)(kr + 32 + l4 * 8 + 4);
    }

    // ---- L1 SWAPPED: acc_n = Wb^T(tile n) @ K^T -> lane holds
    //      H[t=l15][h=16n+l4*4+i]; sigmoid+pack -> L2 A-frags (no LDS!) ----
    f16x4 pH[5];
    #pragma unroll
    for (int n = 0; n < 5; ++n) {
      f32x4 acc = {0.f, 0.f, 0.f, 0.f};
      acc = __builtin_amdgcn_mfma_f32_16x16x32_f16(bf0[n], ka, acc, 0, 0, 0);
      acc = __builtin_amdgcn_mfma_f32_16x16x32_f16(bf1[n], kc, acc, 0, 0, 0);
      pH[n] = pack4(fsig(acc[0] + qh2[n][0]), fsig(acc[1] + qh2[n][1]),
                    fsig(acc[2] + qh2[n][2]), fsig(acc[3] + qh2[n][3]));
    }

    // ---- L2: G = H @ W2 via 16x16x16f16, K=80 in 5 steps; B-frags from
    //      prep-laid global (L1-hot). Output: lane holds G[r=l4*4+i][colt*16+l15].
    float sc[4] = {0.f, 0.f, 0.f, 0.f};
    #pragma unroll
    for (int colt = 0; colt < 3; ++colt) {
      f32x4 acc = {0.f, 0.f, 0.f, 0.f};
      #pragma unroll
      for (int n = 0; n < 5; ++n) {
        f16x4 bw = *(const f16x4*)&g_w2f[((colt * 5 + n) * 64 + lane) * 4];
        acc = __builtin_amdgcn_mfma_f32_16x16x16f16(pH[n], bw, acc, 0, 0, 0);
      }
      #pragma unroll
      for (int i = 0; i < 4; ++i)
        sc[i] += fsig(acc[i] + b2v[colt]) * w3v[colt];
    }
    // ---- reduce over the 16 cols (l15) via DPP row_ror ----
    #pragma unroll
    for (int i = 0; i < 4; ++i) sc[i] = row16_sum(sc[i]);
    if (l15 == 0) {
      #pragma unroll
      for (int i = 0; i < 4; ++i) {
        int rr = mt * 16 + l4 * 4 + i;
        sSw[l4 * 4 + i] = (rr < len) ? sc[i] + b3v : 0.0f;
      }
    }
    // broadcast this lane's row score (same-wave LDS, in-order per wave)
    float sv = sSw[l15];
    #pragma unroll
    for (int j = 0; j < 8; ++j) {
      poolA[j] += sv * (float)ka[j];
      poolB[j] += sv * (float)kc[j];
    }
  }

  // ---- reduce pooling over the 16 rows (l15) via DPP row_ror ----
  #pragma unroll
  for (int j = 0; j < 8; ++j) {
    poolA[j] = row16_sum(poolA[j]);
    poolB[j] = row16_sum(poolB[j]);
  }
  if (l15 == 0) {
    float* ob = out + (size_t)b * En;
    #pragma unroll
    for (int j = 0; j < 8; ++j) {
      atomicAdd(&ob[l4 * 8 + j], poolA[j]);
      atomicAdd(&ob[32 + l4 * 8 + j], poolB[j]);
    }
  }
}

extern "C" void kernel_launch(void* const* d_in, const int* in_sizes, int n_in,
                              void* d_out, int out_size, void* d_ws, size_t ws_size,
                              hipStream_t stream) {
  const float* query       = (const float*)d_in[0];
  const float* keys        = (const float*)d_in[1];
  const int*   keys_length = (const int*)d_in[2];
  const float* W1 = (const float*)d_in[3];
  const float* b1 = (const float*)d_in[4];
  const float* W2 = (const float*)d_in[5];
  const float* b2 = (const float*)d_in[6];
  const float* W3 = (const float*)d_in[7];
  const float* b3 = (const float*)d_in[8];
  float* out = (float*)d_out;

  hipMemsetAsync(out, 0, (size_t)Bn * En * sizeof(float), stream);
  hipLaunchKernelGGL(din_prep, dim3(20), dim3(256), 0, stream, W1, W2);
  hipLaunchKernelGGL(din_main, dim3(Bn * 2), dim3(64), 0, stream,
                     query, keys, keys_length, b1, b2, W3, b3, out);
}

// Round 16
// 63.276 us; speedup vs baseline: 1.1635x; 1.1635x over previous
//
#include <hip/hip_runtime.h>

// DIN attention pooling — round 16: R13 per-wave code, 1.5x resident waves.
//   Wb[e][h] = (W1b-W1c)[e][h] + q_e*W1d[e][h];  qh[h] = b1[h] + q @ (W1a+W1c)
//   H = sig(K@Wb + qh); G = sig(H@W2 + b2); s = G@W3 + b3 (masked); out = s^T K
// R14 (2-slab pipeline) and R15 (operand-swap, no LDS) BOTH regressed =>
// chain restructuring is not the lever at 4 waves/SIMD; residency is.
// 1-wave blocks cap at 16 WG/CU = 16 waves/CU. R16: 4-wave blocks with fully
// independent waves (no barriers), wave = (b, third): 6144 waves in 1536
// blocks = 24 waves/CU = 6/SIMD (VGPR 84 allows exactly 6). Segment merge via
// atomicAdd (d_out pre-zeroed). Inner loop byte-identical to R13.
// REGISTER LAW (R6/R8/R11 vs R7/R9/R12): keep the 170-reg class (bound ,3).

constexpr int Bn = 2048, Tn = 200, En = 64;
constexpr int HS_W  = 84;                // H slab stride (f16), conflict-free
constexpr int HSLAB = 16 * HS_W + 48;    // 1392: covers row-15 aH2 read to 1388

typedef _Float16 f16;
typedef _Float16 f16x2 __attribute__((ext_vector_type(2)));
typedef _Float16 f16x8 __attribute__((ext_vector_type(8)));
typedef float f32x4 __attribute__((ext_vector_type(4)));

__device__ __align__(16) f16 g_wkf[80 * 64];    // [h][e]  W1b - W1c
__device__ __align__(16) f16 g_wqf[80 * 64];    // [h][e]  W1d
__device__ __align__(16) f16 g_wsumT[80 * 64];  // [h][e]  W1a + W1c
__device__ __align__(16) f16 g_w2t[48 * 96];    // [j][h]  W2^T, zeros j>=40 or h>=80

__device__ __forceinline__ float fsig(float x) {
  return __fdividef(1.0f, 1.0f + __expf(-x));
}

template <int CTRL>
__device__ __forceinline__ float dpp_add(float x) {
  int y = __builtin_amdgcn_update_dpp(0, __builtin_bit_cast(int, x),
                                      CTRL, 0xf, 0xf, true);
  return x + __builtin_bit_cast(float, y);
}
__device__ __forceinline__ float row16_sum(float x) {
  x = dpp_add<0x121>(x);
  x = dpp_add<0x122>(x);
  x = dpp_add<0x124>(x);
  x = dpp_add<0x128>(x);
  return x;
}

__device__ __forceinline__ f16x8 pack8(float4 a, float4 b) {
  union { f16x2 p[4]; f16x8 v; } u;
  u.p[0] = __builtin_bit_cast(f16x2, __builtin_amdgcn_cvt_pkrtz(a.x, a.y));
  u.p[1] = __builtin_bit_cast(f16x2, __builtin_amdgcn_cvt_pkrtz(a.z, a.w));
  u.p[2] = __builtin_bit_cast(f16x2, __builtin_amdgcn_cvt_pkrtz(b.x, b.y));
  u.p[3] = __builtin_bit_cast(f16x2, __builtin_amdgcn_cvt_pkrtz(b.z, b.w));
  return u.v;
}

__global__ __launch_bounds__(256) void din_prep(const float* __restrict__ W1,
                                                const float* __restrict__ W2) {
  int idx = blockIdx.x * 256 + threadIdx.x;   // grid 20 -> 5120
  if (idx < 5120) {
    int h = idx >> 6, e = idx & 63;
    float wa = W1[e * 80 + h], wb = W1[(64 + e) * 80 + h];
    float wc = W1[(128 + e) * 80 + h], wd = W1[(192 + e) * 80 + h];
    g_wkf[idx] = (f16)(wb - wc);
    g_wqf[idx] = (f16)wd;
    g_wsumT[idx] = (f16)(wa + wc);
  }
  if (idx < 4608) {
    int j = idx / 96, h = idx - j * 96;
    g_w2t[idx] = (h < 80 && j < 40) ? (f16)W2[h * 40 + j] : (f16)0.0f;
  }
}

__global__ __launch_bounds__(256, 3) void din_main(
    const float* __restrict__ query,
    const float* __restrict__ keys,
    const int*   __restrict__ keys_length,
    const float* __restrict__ b1,
    const float* __restrict__ b2,
    const float* __restrict__ W3,
    const float* __restrict__ b3,
    float* __restrict__ out)
{
  __shared__ __align__(16) f16 sHall[4][HSLAB];   // 11,136 B (per-wave slabs)
  __shared__ float sSwAll[4][16];                 //    256 B

  const int tid  = threadIdx.x;
  const int lane = tid & 63;
  const int wid  = tid >> 6;
  const int l15  = lane & 15;
  const int l4   = lane >> 4;

  // wave -> (b, third). 1536 blocks x 4 waves = 6144 waves = 2048 b x 3 segs.
  const int gw  = blockIdx.x * 4 + wid;
  const int b   = gw / 3;
  const int seg = gw - b * 3;
  const int mts = (seg == 0) ? 0 : (1 + seg * 4);   // 0 / 5 / 9
  const int mte = mts + ((seg == 0) ? 5 : 4);       // 5 / 9 / 13

  const float* qp = query + (size_t)b * En;
  const float* kb = keys + (size_t)b * Tn * En;
  const int len = keys_length[b];
  const float b3v = b3[0];

  f16* hs = sHall[wid];
  float* sSw = sSwAll[wid];

  // ---- zero own slab (cols 80..95 + pad must read 0.0 in L2 MFMAs) ----
  const f16x8 zf = (f16x8)(f16)0.0f;
  for (int i = lane * 8; i < HSLAB; i += 512) *(f16x8*)&hs[i] = zf;

  // ---- q fragments (f16) ----
  f16x8 qf0, qf1;
  {
    float4 qa = *(const float4*)(qp + l4 * 8);
    float4 qb = *(const float4*)(qp + l4 * 8 + 4);
    float4 qc = *(const float4*)(qp + 32 + l4 * 8);
    float4 qd = *(const float4*)(qp + 32 + l4 * 8 + 4);
    qf0 = pack8(qa, qb);
    qf1 = pack8(qc, qd);
  }

  // ---- qh[c] = b1[c] + q @ wsum[:,c] via VALU dot + shfl over l4 ----
  float qhv[5];
  #pragma unroll
  for (int n = 0; n < 5; ++n) {
    int c = n * 16 + l15;
    f16x8 ws0 = *(const f16x8*)&g_wsumT[c * 64 + l4 * 8];
    f16x8 ws1 = *(const f16x8*)&g_wsumT[c * 64 + 32 + l4 * 8];
    float p = 0.f;
    #pragma unroll
    for (int j = 0; j < 8; ++j)
      p += (float)qf0[j] * (float)ws0[j] + (float)qf1[j] * (float)ws1[j];
    p += __shfl_xor(p, 16, 64);
    p += __shfl_xor(p, 32, 64);
    qhv[n] = p + b1[c];
  }

  // ---- L1 B-fragments: Wb = wk + q*wqk (elementwise f16) ----
  f16x8 bf0[5], bf1[5];
  #pragma unroll
  for (int n = 0; n < 5; ++n) {
    int c = n * 16 + l15;
    bf0[n] = *(const f16x8*)&g_wkf[c * 64 + l4 * 8]
           + qf0 * *(const f16x8*)&g_wqf[c * 64 + l4 * 8];
    bf1[n] = *(const f16x8*)&g_wkf[c * 64 + 32 + l4 * 8]
           + qf1 * *(const f16x8*)&g_wqf[c * 64 + 32 + l4 * 8];
  }

  // ---- per-col constants for L2/L3 ----
  float b2v[3], w3v[3];
  #pragma unroll
  for (int n = 0; n < 3; ++n) {
    int c = n * 16 + l15;
    b2v[n] = (c < 40) ? b2[c] : 0.0f;
    w3v[n] = (c < 40) ? W3[c] : 0.0f;
  }

  float poolA[8] = {0,0,0,0,0,0,0,0};
  float poolB[8] = {0,0,0,0,0,0,0,0};

  // ---- prefetch first tile's keys rows ----
  float4 p0, p1, p2, p3;
  {
    int r = mts * 16 + l15; const float* kr = kb + (r < Tn ? r : Tn - 1) * 64;
    p0 = *(const float4*)(kr + l4 * 8);
    p1 = *(const float4*)(kr + l4 * 8 + 4);
    p2 = *(const float4*)(kr + 32 + l4 * 8);
    p3 = *(const float4*)(kr + 32 + l4 * 8 + 4);
  }

  for (int mt = mts; mt < mte; ++mt) {
    f16x8 ka = pack8(p0, p1);
    f16x8 kc = pack8(p2, p3);
    // issue next tile's loads under this tile's compute
    if (mt + 1 < mte) {
      int r = (mt + 1) * 16 + l15; const float* kr = kb + (r < Tn ? r : Tn - 1) * 64;
      p0 = *(const float4*)(kr + l4 * 8);
      p1 = *(const float4*)(kr + l4 * 8 + 4);
      p2 = *(const float4*)(kr + 32 + l4 * 8);
      p3 = *(const float4*)(kr + 32 + l4 * 8 + 4);
    }

    // L1 + sigmoid -> H slab, per n (acc liveness = 4)
    #pragma unroll
    for (int n = 0; n < 5; ++n) {
      f32x4 acc = {0.f, 0.f, 0.f, 0.f};
      acc = __builtin_amdgcn_mfma_f32_16x16x32_f16(ka, bf0[n], acc, 0, 0, 0);
      acc = __builtin_amdgcn_mfma_f32_16x16x32_f16(kc, bf1[n], acc, 0, 0, 0);
      int c = n * 16 + l15;
      #pragma unroll
      for (int i = 0; i < 4; ++i)
        hs[(l4 * 4 + i) * HS_W + c] = (f16)fsig(acc[i] + qhv[n]);
    }
    // H^T A-frags
    f16x8 aH0 = *(const f16x8*)&hs[l15 * HS_W + l4 * 8];
    f16x8 aH1 = *(const f16x8*)&hs[l15 * HS_W + 32 + l4 * 8];
    f16x8 aH2 = *(const f16x8*)&hs[l15 * HS_W + 64 + l4 * 8];

    // L2 (B-frags from global g_w2t, L1-cache-hot) + sigmoid + W3 dot
    float sc[4] = {0.f, 0.f, 0.f, 0.f};
    #pragma unroll
    for (int n = 0; n < 3; ++n) {
      int c = n * 16 + l15;
      f32x4 acc = {0.f, 0.f, 0.f, 0.f};
      acc = __builtin_amdgcn_mfma_f32_16x16x32_f16(aH0, *(const f16x8*)&g_w2t[c * 96 + l4 * 8], acc, 0, 0, 0);
      acc = __builtin_amdgcn_mfma_f32_16x16x32_f16(aH1, *(const f16x8*)&g_w2t[c * 96 + 32 + l4 * 8], acc, 0, 0, 0);
      acc = __builtin_amdgcn_mfma_f32_16x16x32_f16(aH2, *(const f16x8*)&g_w2t[c * 96 + 64 + l4 * 8], acc, 0, 0, 0);
      #pragma unroll
      for (int i = 0; i < 4; ++i)
        sc[i] += fsig(acc[i] + b2v[n]) * w3v[n];
    }
    // reduce score over the 16 cols (l15) via DPP row_ror — no LDS pipe
    #pragma unroll
    for (int i = 0; i < 4; ++i) sc[i] = row16_sum(sc[i]);
    if (l15 == 0) {
      #pragma unroll
      for (int i = 0; i < 4; ++i) {
        int rr = mt * 16 + l4 * 4 + i;
        sSw[l4 * 4 + i] = (rr < len) ? sc[i] + b3v : 0.0f;
      }
    }
    // broadcast this lane's row score (same-wave LDS, in-order per wave)
    float sv = sSw[l15];
    #pragma unroll
    for (int j = 0; j < 8; ++j) {
      poolA[j] += sv * (float)ka[j];
      poolB[j] += sv * (float)kc[j];
    }
  }

  // ---- reduce pooling over the 16 rows (l15) via DPP row_ror ----
  #pragma unroll
  for (int j = 0; j < 8; ++j) {
    poolA[j] = row16_sum(poolA[j]);
    poolB[j] = row16_sum(poolB[j]);
  }
  if (l15 == 0) {
    float* ob = out + (size_t)b * En;
    #pragma unroll
    for (int j = 0; j < 8; ++j) {
      atomicAdd(&ob[l4 * 8 + j], poolA[j]);
      atomicAdd(&ob[32 + l4 * 8 + j], poolB[j]);
    }
  }
}

extern "C" void kernel_launch(void* const* d_in, const int* in_sizes, int n_in,
                              void* d_out, int out_size, void* d_ws, size_t ws_size,
                              hipStream_t stream) {
  const float* query       = (const float*)d_in[0];
  const float* keys        = (const float*)d_in[1];
  const int*   keys_length = (const int*)d_in[2];
  const float* W1 = (const float*)d_in[3];
  const float* b1 = (const float*)d_in[4];
  const float* W2 = (const float*)d_in[5];
  const float* b2 = (const float*)d_in[6];
  const float* W3 = (const float*)d_in[7];
  const float* b3 = (const float*)d_in[8];
  float* out = (float*)d_out;

  hipMemsetAsync(out, 0, (size_t)Bn * En * sizeof(float), stream);
  hipLaunchKernelGGL(din_prep, dim3(20), dim3(256), 0, stream, W1, W2);
  hipLaunchKernelGGL(din_main, dim3(1536), dim3(256), 0, stream,
                     query, keys, keys_length, b1, b2, W3, b3, out);
}

// Round 17
// 59.248 us; speedup vs baseline: 1.2425x; 1.0680x over previous
//
#include <hip/hip_runtime.h>

// DIN attention pooling — round 17: R13 + hoisted loop-invariant W2 B-frags.
//   Wb[e][h] = (W1b-W1c)[e][h] + q_e*W1d[e][h];  qh[h] = b1[h] + q @ (W1a+W1c)
//   H = sig(K@Wb + qh); G = sig(H@W2 + b2); s = G@W3 + b3 (masked); out = s^T K
// R14/R15 (chain restructure) and R16 (3-split residency) all regressed vs
// R13. R13's remaining in-loop stall: 9 g_w2t B-frag VMEM loads per tile with
// loop-invariant addresses that the compiler did NOT hoist (VGPR=84). R17
// pre-loads them into 36 registers before the loop — in-loop VMEM is then
// only the overlapped keys prefetch. Live set ~125 regs < 170 budget.
// REGISTER LAW (R6/R8/R11 vs R7/R9/R12): keep the 170-reg class (bound ,3).

constexpr int Bn = 2048, Tn = 200, En = 64;
constexpr int HS_W  = 84;                // H slab stride (f16), conflict-free
constexpr int HSLAB = 16 * HS_W + 48;    // 1392: covers row-15 aH2 read to 1388

typedef _Float16 f16;
typedef _Float16 f16x2 __attribute__((ext_vector_type(2)));
typedef _Float16 f16x8 __attribute__((ext_vector_type(8)));
typedef float f32x4 __attribute__((ext_vector_type(4)));

__device__ __align__(16) f16 g_wkf[80 * 64];    // [h][e]  W1b - W1c
__device__ __align__(16) f16 g_wqf[80 * 64];    // [h][e]  W1d
__device__ __align__(16) f16 g_wsumT[80 * 64];  // [h][e]  W1a + W1c
__device__ __align__(16) f16 g_w2t[48 * 96];    // [j][h]  W2^T, zeros j>=40 or h>=80

__device__ __forceinline__ float fsig(float x) {
  return __fdividef(1.0f, 1.0f + __expf(-x));
}

template <int CTRL>
__device__ __forceinline__ float dpp_add(float x) {
  int y = __builtin_amdgcn_update_dpp(0, __builtin_bit_cast(int, x),
                                      CTRL, 0xf, 0xf, true);
  return x + __builtin_bit_cast(float, y);
}
__device__ __forceinline__ float row16_sum(float x) {
  x = dpp_add<0x121>(x);
  x = dpp_add<0x122>(x);
  x = dpp_add<0x124>(x);
  x = dpp_add<0x128>(x);
  return x;
}

__device__ __forceinline__ f16x8 pack8(float4 a, float4 b) {
  union { f16x2 p[4]; f16x8 v; } u;
  u.p[0] = __builtin_bit_cast(f16x2, __builtin_amdgcn_cvt_pkrtz(a.x, a.y));
  u.p[1] = __builtin_bit_cast(f16x2, __builtin_amdgcn_cvt_pkrtz(a.z, a.w));
  u.p[2] = __builtin_bit_cast(f16x2, __builtin_amdgcn_cvt_pkrtz(b.x, b.y));
  u.p[3] = __builtin_bit_cast(f16x2, __builtin_amdgcn_cvt_pkrtz(b.z, b.w));
  return u.v;
}

__global__ __launch_bounds__(256) void din_prep(const float* __restrict__ W1,
                                                const float* __restrict__ W2) {
  int idx = blockIdx.x * 256 + threadIdx.x;   // grid 20 -> 5120
  if (idx < 5120) {
    int h = idx >> 6, e = idx & 63;
    float wa = W1[e * 80 + h], wb = W1[(64 + e) * 80 + h];
    float wc = W1[(128 + e) * 80 + h], wd = W1[(192 + e) * 80 + h];
    g_wkf[idx] = (f16)(wb - wc);
    g_wqf[idx] = (f16)wd;
    g_wsumT[idx] = (f16)(wa + wc);
  }
  if (idx < 4608) {
    int j = idx / 96, h = idx - j * 96;
    g_w2t[idx] = (h < 80 && j < 40) ? (f16)W2[h * 40 + j] : (f16)0.0f;
  }
}

__global__ __launch_bounds__(64, 3) void din_main(
    const float* __restrict__ query,
    const float* __restrict__ keys,
    const int*   __restrict__ keys_length,
    const float* __restrict__ b1,
    const float* __restrict__ b2,
    const float* __restrict__ W3,
    const float* __restrict__ b3,
    float* __restrict__ out)
{
  __shared__ __align__(16) f16 hs[HSLAB];   // 2,784 B (one wave per block)
  __shared__ float sSw[16];

  const int lane = threadIdx.x;
  const int l15 = lane & 15;
  const int l4  = lane >> 4;

  const int b    = blockIdx.x >> 1;
  const int half = blockIdx.x & 1;
  const int mts  = half ? 7 : 0;
  const int mte  = half ? 13 : 7;

  const float* qp = query + (size_t)b * En;
  const float* kb = keys + (size_t)b * Tn * En;
  const int len = keys_length[b];
  const float b3v = b3[0];

  // ---- zero slab (cols 80..95 + pad must read 0.0 in L2 MFMAs) ----
  const f16x8 zf = (f16x8)(f16)0.0f;
  for (int i = lane * 8; i < HSLAB; i += 512) *(f16x8*)&hs[i] = zf;

  // ---- HOISTED loop-invariant W2 B-frags: bw[n][ks], 9 x f16x8 = 36 VGPRs --
  f16x8 bw[3][3];
  #pragma unroll
  for (int n = 0; n < 3; ++n) {
    int c = n * 16 + l15;
    #pragma unroll
    for (int ks = 0; ks < 3; ++ks)
      bw[n][ks] = *(const f16x8*)&g_w2t[c * 96 + ks * 32 + l4 * 8];
  }

  // ---- q fragments (f16) ----
  f16x8 qf0, qf1;
  {
    float4 qa = *(const float4*)(qp + l4 * 8);
    float4 qb = *(const float4*)(qp + l4 * 8 + 4);
    float4 qc = *(const float4*)(qp + 32 + l4 * 8);
    float4 qd = *(const float4*)(qp + 32 + l4 * 8 + 4);
    qf0 = pack8(qa, qb);
    qf1 = pack8(qc, qd);
  }

  // ---- qh[c] = b1[c] + q @ wsum[:,c] via VALU dot + shfl over l4 ----
  float qhv[5];
  #pragma unroll
  for (int n = 0; n < 5; ++n) {
    int c = n * 16 + l15;
    f16x8 ws0 = *(const f16x8*)&g_wsumT[c * 64 + l4 * 8];
    f16x8 ws1 = *(const f16x8*)&g_wsumT[c * 64 + 32 + l4 * 8];
    float p = 0.f;
    #pragma unroll
    for (int j = 0; j < 8; ++j)
      p += (float)qf0[j] * (float)ws0[j] + (float)qf1[j] * (float)ws1[j];
    p += __shfl_xor(p, 16, 64);
    p += __shfl_xor(p, 32, 64);
    qhv[n] = p + b1[c];
  }

  // ---- L1 B-fragments: Wb = wk + q*wqk (elementwise f16) ----
  f16x8 bf0[5], bf1[5];
  #pragma unroll
  for (int n = 0; n < 5; ++n) {
    int c = n * 16 + l15;
    bf0[n] = *(const f16x8*)&g_wkf[c * 64 + l4 * 8]
           + qf0 * *(const f16x8*)&g_wqf[c * 64 + l4 * 8];
    bf1[n] = *(const f16x8*)&g_wkf[c * 64 + 32 + l4 * 8]
           + qf1 * *(const f16x8*)&g_wqf[c * 64 + 32 + l4 * 8];
  }

  // ---- per-col constants for L2/L3 ----
  float b2v[3], w3v[3];
  #pragma unroll
  for (int n = 0; n < 3; ++n) {
    int c = n * 16 + l15;
    b2v[n] = (c < 40) ? b2[c] : 0.0f;
    w3v[n] = (c < 40) ? W3[c] : 0.0f;
  }

  float poolA[8] = {0,0,0,0,0,0,0,0};
  float poolB[8] = {0,0,0,0,0,0,0,0};

  // ---- prefetch first tile's keys rows ----
  float4 p0, p1, p2, p3;
  {
    int r = mts * 16 + l15; const float* kr = kb + (r < Tn ? r : Tn - 1) * 64;
    p0 = *(const float4*)(kr + l4 * 8);
    p1 = *(const float4*)(kr + l4 * 8 + 4);
    p2 = *(const float4*)(kr + 32 + l4 * 8);
    p3 = *(const float4*)(kr + 32 + l4 * 8 + 4);
  }

  for (int mt = mts; mt < mte; ++mt) {
    f16x8 ka = pack8(p0, p1);
    f16x8 kc = pack8(p2, p3);
    // issue next tile's loads under this tile's compute
    if (mt + 1 < mte) {
      int r = (mt + 1) * 16 + l15; const float* kr = kb + (r < Tn ? r : Tn - 1) * 64;
      p0 = *(const float4*)(kr + l4 * 8);
      p1 = *(const float4*)(kr + l4 * 8 + 4);
      p2 = *(const float4*)(kr + 32 + l4 * 8);
      p3 = *(const float4*)(kr + 32 + l4 * 8 + 4);
    }

    // L1 + sigmoid -> H slab, per n (acc liveness = 4)
    #pragma unroll
    for (int n = 0; n < 5; ++n) {
      f32x4 acc = {0.f, 0.f, 0.f, 0.f};
      acc = __builtin_amdgcn_mfma_f32_16x16x32_f16(ka, bf0[n], acc, 0, 0, 0);
      acc = __builtin_amdgcn_mfma_f32_16x16x32_f16(kc, bf1[n], acc, 0, 0, 0);
      int c = n * 16 + l15;
      #pragma unroll
      for (int i = 0; i < 4; ++i)
        hs[(l4 * 4 + i) * HS_W + c] = (f16)fsig(acc[i] + qhv[n]);
    }
    // H^T A-frags
    f16x8 aH0 = *(const f16x8*)&hs[l15 * HS_W + l4 * 8];
    f16x8 aH1 = *(const f16x8*)&hs[l15 * HS_W + 32 + l4 * 8];
    f16x8 aH2 = *(const f16x8*)&hs[l15 * HS_W + 64 + l4 * 8];

    // L2 (hoisted register B-frags) + sigmoid + W3 dot
    float sc[4] = {0.f, 0.f, 0.f, 0.f};
    #pragma unroll
    for (int n = 0; n < 3; ++n) {
      f32x4 acc = {0.f, 0.f, 0.f, 0.f};
      acc = __builtin_amdgcn_mfma_f32_16x16x32_f16(aH0, bw[n][0], acc, 0, 0, 0);
      acc = __builtin_amdgcn_mfma_f32_16x16x32_f16(aH1, bw[n][1], acc, 0, 0, 0);
      acc = __builtin_amdgcn_mfma_f32_16x16x32_f16(aH2, bw[n][2], acc, 0, 0, 0);
      #pragma unroll
      for (int i = 0; i < 4; ++i)
        sc[i] += fsig(acc[i] + b2v[n]) * w3v[n];
    }
    // reduce score over the 16 cols (l15) via DPP row_ror — no LDS pipe
    #pragma unroll
    for (int i = 0; i < 4; ++i) sc[i] = row16_sum(sc[i]);
    if (l15 == 0) {
      #pragma unroll
      for (int i = 0; i < 4; ++i) {
        int rr = mt * 16 + l4 * 4 + i;
        sSw[l4 * 4 + i] = (rr < len) ? sc[i] + b3v : 0.0f;
      }
    }
    // broadcast this lane's row score (same-wave LDS, in-order per wave)
    float sv = sSw[l15];
    #pragma unroll
    for (int j = 0; j < 8; ++j) {
      poolA[j] += sv * (float)ka[j];
      poolB[j] += sv * (float)kc[j];
    }
  }

  // ---- reduce pooling over the 16 rows (l15) via DPP row_ror ----
  #pragma unroll
  for (int j = 0; j < 8; ++j) {
    poolA[j] = row16_sum(poolA[j]);
    poolB[j] = row16_sum(poolB[j]);
  }
  if (l15 == 0) {
    float* ob = out + (size_t)b * En;
    #pragma unroll
    for (int j = 0; j < 8; ++j) {
      atomicAdd(&ob[l4 * 8 + j], poolA[j]);
      atomicAdd(&ob[32 + l4 * 8 + j], poolB[j]);
    }
  }
}

extern "C" void kernel_launch(void* const* d_in, const int* in_sizes, int n_in,
                              void* d_out, int out_size, void* d_ws, size_t ws_size,
                              hipStream_t stream) {
  const float* query       = (const float*)d_in[0];
  const float* keys        = (const float*)d_in[1];
  const int*   keys_length = (const int*)d_in[2];
  const float* W1 = (const float*)d_in[3];
  const float* b1 = (const float*)d_in[4];
  const float* W2 = (const float*)d_in[5];
  const float* b2 = (const float*)d_in[6];
  const float* W3 = (const float*)d_in[7];
  const float* b3 = (const float*)d_in[8];
  float* out = (float*)d_out;

  hipMemsetAsync(out, 0, (size_t)Bn * En * sizeof(float), stream);
  hipLaunchKernelGGL(din_prep, dim3(20), dim3(256), 0, stream, W1, W2);
  hipLaunchKernelGGL(din_main, dim3(Bn * 2), dim3(64), 0, stream,
                     query, keys, keys_length, b1, b2, W3, b3, out);
}

// Round 18
// 52.046 us; speedup vs baseline: 1.4145x; 1.1384x over previous
//
#include <hip/hip_runtime.h>

// DIN attention pooling — round 18: full-b waves (setup amortized 2x).
//   Wb[e][h] = (W1b-W1c)[e][h] + q_e*W1d[e][h];  qh[h] = b1[h] + q @ (W1a+W1c)
//   H = sig(K@Wb + qh); G = sig(H@W2 + b2); s = G@W3 + b3 (masked); out = s^T K
// Evidence R16: 1.5x waves -> VALUBusy up but time UP => per-wave setup
// (30KB weight loads + qh dot + bf build) is a big fixed cost. R18 goes the
// other way: wave = FULL b (13 tiles), 2048 waves — setup instances halved,
// effective residency unchanged (~8 waves/CU measured across R13-R17).
// Wave owns its whole output row: plain store, no atomicAdd, no memset.
// REGISTER LAW (R6/R8/R11 vs R7/R9/R12): keep the 170-reg class (bound ,3).

constexpr int Bn = 2048, Tn = 200, En = 64;
constexpr int HS_W  = 84;                // H slab stride (f16), conflict-free
constexpr int HSLAB = 16 * HS_W + 48;    // 1392: covers row-15 aH2 read to 1388

typedef _Float16 f16;
typedef _Float16 f16x2 __attribute__((ext_vector_type(2)));
typedef _Float16 f16x8 __attribute__((ext_vector_type(8)));
typedef float f32x4 __attribute__((ext_vector_type(4)));

__device__ __align__(16) f16 g_wkf[80 * 64];    // [h][e]  W1b - W1c
__device__ __align__(16) f16 g_wqf[80 * 64];    // [h][e]  W1d
__device__ __align__(16) f16 g_wsumT[80 * 64];  // [h][e]  W1a + W1c
__device__ __align__(16) f16 g_w2t[48 * 96];    // [j][h]  W2^T, zeros j>=40 or h>=80

__device__ __forceinline__ float fsig(float x) {
  return __fdividef(1.0f, 1.0f + __expf(-x));
}

template <int CTRL>
__device__ __forceinline__ float dpp_add(float x) {
  int y = __builtin_amdgcn_update_dpp(0, __builtin_bit_cast(int, x),
                                      CTRL, 0xf, 0xf, true);
  return x + __builtin_bit_cast(float, y);
}
__device__ __forceinline__ float row16_sum(float x) {
  x = dpp_add<0x121>(x);
  x = dpp_add<0x122>(x);
  x = dpp_add<0x124>(x);
  x = dpp_add<0x128>(x);
  return x;
}

__device__ __forceinline__ f16x8 pack8(float4 a, float4 b) {
  union { f16x2 p[4]; f16x8 v; } u;
  u.p[0] = __builtin_bit_cast(f16x2, __builtin_amdgcn_cvt_pkrtz(a.x, a.y));
  u.p[1] = __builtin_bit_cast(f16x2, __builtin_amdgcn_cvt_pkrtz(a.z, a.w));
  u.p[2] = __builtin_bit_cast(f16x2, __builtin_amdgcn_cvt_pkrtz(b.x, b.y));
  u.p[3] = __builtin_bit_cast(f16x2, __builtin_amdgcn_cvt_pkrtz(b.z, b.w));
  return u.v;
}

__global__ __launch_bounds__(256) void din_prep(const float* __restrict__ W1,
                                                const float* __restrict__ W2) {
  int idx = blockIdx.x * 256 + threadIdx.x;   // grid 20 -> 5120
  if (idx < 5120) {
    int h = idx >> 6, e = idx & 63;
    float wa = W1[e * 80 + h], wb = W1[(64 + e) * 80 + h];
    float wc = W1[(128 + e) * 80 + h], wd = W1[(192 + e) * 80 + h];
    g_wkf[idx] = (f16)(wb - wc);
    g_wqf[idx] = (f16)wd;
    g_wsumT[idx] = (f16)(wa + wc);
  }
  if (idx < 4608) {
    int j = idx / 96, h = idx - j * 96;
    g_w2t[idx] = (h < 80 && j < 40) ? (f16)W2[h * 40 + j] : (f16)0.0f;
  }
}

__global__ __launch_bounds__(64, 3) void din_main(
    const float* __restrict__ query,
    const float* __restrict__ keys,
    const int*   __restrict__ keys_length,
    const float* __restrict__ b1,
    const float* __restrict__ b2,
    const float* __restrict__ W3,
    const float* __restrict__ b3,
    float* __restrict__ out)
{
  __shared__ __align__(16) f16 hs[HSLAB];   // 2,784 B (one wave per block)
  __shared__ float sSw[16];

  const int lane = threadIdx.x;
  const int l15 = lane & 15;
  const int l4  = lane >> 4;

  const int b = blockIdx.x;           // wave = full b, 13 tiles

  const float* qp = query + (size_t)b * En;
  const float* kb = keys + (size_t)b * Tn * En;
  const int len = keys_length[b];
  const float b3v = b3[0];

  // ---- zero slab (cols 80..95 + pad must read 0.0 in L2 MFMAs) ----
  const f16x8 zf = (f16x8)(f16)0.0f;
  for (int i = lane * 8; i < HSLAB; i += 512) *(f16x8*)&hs[i] = zf;

  // ---- HOISTED loop-invariant W2 B-frags: bw[n][ks], 9 x f16x8 = 36 VGPRs --
  f16x8 bw[3][3];
  #pragma unroll
  for (int n = 0; n < 3; ++n) {
    int c = n * 16 + l15;
    #pragma unroll
    for (int ks = 0; ks < 3; ++ks)
      bw[n][ks] = *(const f16x8*)&g_w2t[c * 96 + ks * 32 + l4 * 8];
  }

  // ---- q fragments (f16) ----
  f16x8 qf0, qf1;
  {
    float4 qa = *(const float4*)(qp + l4 * 8);
    float4 qb = *(const float4*)(qp + l4 * 8 + 4);
    float4 qc = *(const float4*)(qp + 32 + l4 * 8);
    float4 qd = *(const float4*)(qp + 32 + l4 * 8 + 4);
    qf0 = pack8(qa, qb);
    qf1 = pack8(qc, qd);
  }

  // ---- qh[c] = b1[c] + q @ wsum[:,c] via VALU dot + shfl over l4 ----
  float qhv[5];
  #pragma unroll
  for (int n = 0; n < 5; ++n) {
    int c = n * 16 + l15;
    f16x8 ws0 = *(const f16x8*)&g_wsumT[c * 64 + l4 * 8];
    f16x8 ws1 = *(const f16x8*)&g_wsumT[c * 64 + 32 + l4 * 8];
    float p = 0.f;
    #pragma unroll
    for (int j = 0; j < 8; ++j)
      p += (float)qf0[j] * (float)ws0[j] + (float)qf1[j] * (float)ws1[j];
    p += __shfl_xor(p, 16, 64);
    p += __shfl_xor(p, 32, 64);
    qhv[n] = p + b1[c];
  }

  // ---- L1 B-fragments: Wb = wk + q*wqk (elementwise f16) ----
  f16x8 bf0[5], bf1[5];
  #pragma unroll
  for (int n = 0; n < 5; ++n) {
    int c = n * 16 + l15;
    bf0[n] = *(const f16x8*)&g_wkf[c * 64 + l4 * 8]
           + qf0 * *(const f16x8*)&g_wqf[c * 64 + l4 * 8];
    bf1[n] = *(const f16x8*)&g_wkf[c * 64 + 32 + l4 * 8]
           + qf1 * *(const f16x8*)&g_wqf[c * 64 + 32 + l4 * 8];
  }

  // ---- per-col constants for L2/L3 ----
  float b2v[3], w3v[3];
  #pragma unroll
  for (int n = 0; n < 3; ++n) {
    int c = n * 16 + l15;
    b2v[n] = (c < 40) ? b2[c] : 0.0f;
    w3v[n] = (c < 40) ? W3[c] : 0.0f;
  }

  float poolA[8] = {0,0,0,0,0,0,0,0};
  float poolB[8] = {0,0,0,0,0,0,0,0};

  // ---- prefetch first tile's keys rows ----
  float4 p0, p1, p2, p3;
  {
    int r = l15; const float* kr = kb + r * 64;
    p0 = *(const float4*)(kr + l4 * 8);
    p1 = *(const float4*)(kr + l4 * 8 + 4);
    p2 = *(const float4*)(kr + 32 + l4 * 8);
    p3 = *(const float4*)(kr + 32 + l4 * 8 + 4);
  }

  for (int mt = 0; mt < 13; ++mt) {
    f16x8 ka = pack8(p0, p1);
    f16x8 kc = pack8(p2, p3);
    // issue next tile's loads under this tile's compute
    if (mt + 1 < 13) {
      int r = (mt + 1) * 16 + l15; const float* kr = kb + (r < Tn ? r : Tn - 1) * 64;
      p0 = *(const float4*)(kr + l4 * 8);
      p1 = *(const float4*)(kr + l4 * 8 + 4);
      p2 = *(const float4*)(kr + 32 + l4 * 8);
      p3 = *(const float4*)(kr + 32 + l4 * 8 + 4);
    }

    // L1 + sigmoid -> H slab, per n (acc liveness = 4)
    #pragma unroll
    for (int n = 0; n < 5; ++n) {
      f32x4 acc = {0.f, 0.f, 0.f, 0.f};
      acc = __builtin_amdgcn_mfma_f32_16x16x32_f16(ka, bf0[n], acc, 0, 0, 0);
      acc = __builtin_amdgcn_mfma_f32_16x16x32_f16(kc, bf1[n], acc, 0, 0, 0);
      int c = n * 16 + l15;
      #pragma unroll
      for (int i = 0; i < 4; ++i)
        hs[(l4 * 4 + i) * HS_W + c] = (f16)fsig(acc[i] + qhv[n]);
    }
    // H^T A-frags
    f16x8 aH0 = *(const f16x8*)&hs[l15 * HS_W + l4 * 8];
    f16x8 aH1 = *(const f16x8*)&hs[l15 * HS_W + 32 + l4 * 8];
    f16x8 aH2 = *(const f16x8*)&hs[l15 * HS_W + 64 + l4 * 8];

    // L2 (hoisted register B-frags) + sigmoid + W3 dot
    float sc[4] = {0.f, 0.f, 0.f, 0.f};
    #pragma unroll
    for (int n = 0; n < 3; ++n) {
      f32x4 acc = {0.f, 0.f, 0.f, 0.f};
      acc = __builtin_amdgcn_mfma_f32_16x16x32_f16(aH0, bw[n][0], acc, 0, 0, 0);
      acc = __builtin_amdgcn_mfma_f32_16x16x32_f16(aH1, bw[n][1], acc, 0, 0, 0);
      acc = __builtin_amdgcn_mfma_f32_16x16x32_f16(aH2, bw[n][2], acc, 0, 0, 0);
      #pragma unroll
      for (int i = 0; i < 4; ++i)
        sc[i] += fsig(acc[i] + b2v[n]) * w3v[n];
    }
    // reduce score over the 16 cols (l15) via DPP row_ror — no LDS pipe
    #pragma unroll
    for (int i = 0; i < 4; ++i) sc[i] = row16_sum(sc[i]);
    if (l15 == 0) {
      #pragma unroll
      for (int i = 0; i < 4; ++i) {
        int rr = mt * 16 + l4 * 4 + i;
        sSw[l4 * 4 + i] = (rr < len) ? sc[i] + b3v : 0.0f;
      }
    }
    // broadcast this lane's row score (same-wave LDS, in-order per wave)
    float sv = sSw[l15];
    #pragma unroll
    for (int j = 0; j < 8; ++j) {
      poolA[j] += sv * (float)ka[j];
      poolB[j] += sv * (float)kc[j];
    }
  }

  // ---- reduce pooling over the 16 rows (l15) via DPP row_ror ----
  #pragma unroll
  for (int j = 0; j < 8; ++j) {
    poolA[j] = row16_sum(poolA[j]);
    poolB[j] = row16_sum(poolB[j]);
  }
  // wave owns the full b: plain store (no atomics, no memset)
  if (l15 == 0) {
    float* ob = out + (size_t)b * En;
    #pragma unroll
    for (int j = 0; j < 8; ++j) {
      ob[l4 * 8 + j] = poolA[j];
      ob[32 + l4 * 8 + j] = poolB[j];
    }
  }
}

extern "C" void kernel_launch(void* const* d_in, const int* in_sizes, int n_in,
                              void* d_out, int out_size, void* d_ws, size_t ws_size,
                              hipStream_t stream) {
  const float* query       = (const float*)d_in[0];
  const float* keys        = (const float*)d_in[1];
  const int*   keys_length = (const int*)d_in[2];
  const float* W1 = (const float*)d_in[3];
  const float* b1 = (const float*)d_in[4];
  const float* W2 = (const float*)d_in[5];
  const float* b2 = (const float*)d_in[6];
  const float* W3 = (const float*)d_in[7];
  const float* b3 = (const float*)d_in[8];
  float* out = (float*)d_out;

  hipLaunchKernelGGL(din_prep, dim3(20), dim3(256), 0, stream, W1, W2);
  hipLaunchKernelGGL(din_main, dim3(Bn), dim3(64), 0, stream,
                     query, keys, keys_length, b1, b2, W3, b3, out);
}